// Round 12
// baseline (411.565 us; speedup 1.0000x reference)
//
#include <hip/hip_runtime.h>
#include <math.h>

#define BB 16
#define NN 128
#define HH 256
#define EE (NN*(NN-1))   // 16256

typedef unsigned short ushort_t;
typedef unsigned int uint_t;
typedef __attribute__((ext_vector_type(8))) short bf16x8;
typedef __attribute__((ext_vector_type(4))) float f32x4;

__device__ __forceinline__ ushort_t f2b(float f) {
  unsigned u = __builtin_bit_cast(unsigned, f);
  unsigned r = (u + 0x7fffu + ((u >> 16) & 1u)) >> 16;
  return (ushort_t)r;
}
__device__ __forceinline__ float blo(uint_t u) {
  return __builtin_bit_cast(float, u << 16);
}
__device__ __forceinline__ float bhi(uint_t u) {
  return __builtin_bit_cast(float, u & 0xffff0000u);
}

// fast tanh: (e-1)/(e+1), e = 2^(2x*log2e); clamped
__device__ __forceinline__ float fast_tanh(float x) {
  float xx = fminf(fmaxf(x, -15.f), 15.f);
  float e = __builtin_amdgcn_exp2f(xx * 2.8853900817779268f);
  return (e - 1.f) * __builtin_amdgcn_rcpf(e + 1.f);
}
__device__ __forceinline__ float fast_sigmoid(float x) {
  float xx = fminf(fmaxf(x, -30.f), 30.f);
  float e = __builtin_amdgcn_exp2f(-xx * 1.4426950408889634f);
  return __builtin_amdgcn_rcpf(1.f + e);
}

// ---------------------------------------------------------------------------
// Kprep: fused  (a) node geometry  (b) bf16 copies  (c) wpk LDS-tiled
// transpose (coalesced both sides).
// blocks [0,8): geom; [8,552): copies; [552,712): wpk transpose.
// wpk[m][k2][h] = bf16(M[h][2k2]) | bf16(M[h][2k2+1])<<16.
// ---------------------------------------------------------------------------
__global__ __launch_bounds__(256) void k_prep(
    const float* __restrict__ inputs, const float* __restrict__ pfield,
    float* __restrict__ geom, float* __restrict__ relf,
    const float* __restrict__ w2, const float* __restrict__ pw2,
    const float* __restrict__ pw1,
    const float* __restrict__ pr_w, const float* __restrict__ pi_w,
    const float* __restrict__ pn_w, const float* __restrict__ hr_w,
    const float* __restrict__ hi_w, const float* __restrict__ hh_w,
    const float* __restrict__ ow1, const float* __restrict__ ow2,
    const float* __restrict__ w1,
    ushort_t* __restrict__ w2b, ushort_t* __restrict__ pw2b,
    ushort_t* __restrict__ pw1b, uint_t* __restrict__ wpk) {
  __shared__ float ltile[64][65];   // 16.6 KB, padded (bank-conflict-free)
  int bid = blockIdx.x;
  int tid = threadIdx.x;

  if (bid < 8) {                    // ---- geom path ----
    int idx = bid * 256 + tid;
    float px = inputs[idx*4+0], py = inputs[idx*4+1];
    float vx = inputs[idx*4+2], vy = inputs[idx*4+3];
    float fx = pfield[idx*2+0], fy = pfield[idx*2+1];
    float th = atan2f(vy, vx);
    float c = cosf(th), s = sinf(th);
    float lpx =  c*px + s*py, lpy = -s*px + c*py;
    float lvx =  c*vx + s*vy, lvy = -s*vx + c*vy;
    float lfx =  c*fx + s*fy, lfy = -s*fx + c*fy;
    float np_ = sqrtf(px*px + py*py + 1e-8f);
    float nv_ = sqrtf(vx*vx + vy*vy + 1e-8f);
    float ang  = atan2f(lpy, lpx);
    float vang = atan2f(lvy, lvx);
    float* g = geom + idx*16;
    g[0]=px; g[1]=py; g[2]=vx; g[3]=vy; g[4]=th; g[5]=c; g[6]=s;
    g[7]=lpx; g[8]=lpy; g[9]=lvx; g[10]=lvy; g[11]=lfx; g[12]=lfy;
    float* r = relf + idx*16;
    r[0]=lpx; r[1]=lpy; r[2]=lvx; r[3]=lvy; r[4]=np_; r[5]=ang; r[6]=nv_; r[7]=vang; r[8]=th;
    r[9]=lpx; r[10]=lpy; r[11]=lvx; r[12]=lvy; r[13]=lfx; r[14]=lfy;
    return;
  }
  if (bid < 552) {                  // ---- bf16 copy path ----
    int idx = (bid - 8) * 256 + tid;
    if (idx < HH*HH) { w2b[idx] = f2b(w2[HH*HH + idx]); return; }
    idx -= HH*HH;
    if (idx < HH*HH) { pw2b[idx] = f2b(pw2[HH*HH + idx]); return; }
    idx -= HH*HH;
    // idx < 8192
    int col = idx >> 5, kk = idx & 31;
    pw1b[idx] = (kk < 24) ? f2b(pw1[col*24 + kk]) : (ushort_t)0;
    return;
  }
  // ---- wpk transpose path: 160 blocks ----
  int tb = bid - 552;               // 0..159
  int m  = tb >> 4;                 // matrix 0..9
  int sub = tb & 15;
  int Hbase  = (sub >> 2) * 64;     // 0,64,128,192
  int k2base = (sub & 3) * 32;      // 0,32,64,96
  const float* src; int sstride, soff;
  if      (m == 0) { src = pr_w; sstride = HH; soff = 0; }
  else if (m == 1) { src = pi_w; sstride = HH; soff = 0; }
  else if (m == 2) { src = pn_w; sstride = HH; soff = 0; }
  else if (m == 3) { src = hr_w; sstride = HH; soff = 0; }
  else if (m == 4) { src = hi_w; sstride = HH; soff = 0; }
  else if (m == 5) { src = hh_w; sstride = HH; soff = 0; }
  else if (m == 6) { src = ow1;  sstride = HH; soff = 0; }
  else if (m == 7) { src = ow2;  sstride = HH; soff = 0; }
  else if (m == 8) { src = w1 + HH*2*HH; sstride = 2*HH; soff = 0; }   // w1a
  else             { src = w1 + HH*2*HH; sstride = 2*HH; soff = HH; }  // w1b
  int wv = tid >> 6, lane = tid & 63;
  // load: 64 rows, each a coalesced 64-f32 strip
  #pragma unroll 4
  for (int i = 0; i < 16; ++i) {
    int rl = wv*16 + i;
    ltile[rl][lane] = src[(Hbase + rl)*sstride + soff + 2*k2base + lane];
  }
  __syncthreads();
  // store: pack pairs, coalesced in h
  int h_l = tid & 63, kslot = tid >> 6;
  uint_t* dst = wpk + m*32768;
  #pragma unroll
  for (int e = 0; e < 8; ++e) {
    int kk = kslot*8 + e;
    uint_t lo = f2b(ltile[h_l][2*kk]);
    uint_t hi = f2b(ltile[h_l][2*kk + 1]);
    dst[(k2base + kk)*256 + Hbase + h_l] = lo | (hi << 16);
  }
}

// ---------------------------------------------------------------------------
// K2: Ha = hidden@W1a.T + b1, Hb = hidden@W1b.T — coalesced packed weights.
// grid 512: block = (node n, batch-quarter), 4 rows each.
// ---------------------------------------------------------------------------
__global__ __launch_bounds__(256) void k_hab(const float* __restrict__ hidden,
                                             const uint_t* __restrict__ wpk,
                                             const float* __restrict__ b1,
                                             float* __restrict__ Ha,
                                             float* __restrict__ Hb) {
  int n = blockIdx.x >> 2, qtr = blockIdx.x & 3;
  int tid = threadIdx.x;
  __shared__ float x[4][HH];
  for (int q = 0; q < 4; ++q) {
    int b = qtr*4 + q;
    x[q][tid] = hidden[(b*NN + n)*HH + tid];
  }
  __syncthreads();
  const uint_t* pA = wpk + 8*32768;
  const uint_t* pB = wpk + 9*32768;
  float accA[4], accB[4];
  float bias = b1[HH + tid];
  #pragma unroll
  for (int q = 0; q < 4; ++q) { accA[q] = bias; accB[q] = 0.f; }
  for (int k2 = 0; k2 < 128; ++k2) {
    uint_t ua = pA[(k2<<8) + tid];
    uint_t ub = pB[(k2<<8) + tid];
    float wa0 = blo(ua), wa1 = bhi(ua);
    float wb0 = blo(ub), wb1 = bhi(ub);
    int k = k2 << 1;
    #pragma unroll
    for (int q = 0; q < 4; ++q) {
      float2 x2 = *(const float2*)(&x[q][k]);
      accA[q] += x2.x*wa0 + x2.y*wa1;
      accB[q] += x2.x*wb0 + x2.y*wb1;
    }
  }
  for (int q = 0; q < 4; ++q) {
    int b = qtr*4 + q;
    Ha[(b*NN + n)*HH + tid] = accA[q];
    Hb[(b*NN + n)*HH + tid] = accB[q];
  }
}

// ---------------------------------------------------------------------------
// K3: per (b, recv j, half): 64 senders per block.
// B1 vectorized ×2 (float2 loads, packed b32 LDS writes); bias folded into
// MFMA acc init; wgt preloaded to 16 VGPRs.
// ---------------------------------------------------------------------------
__global__ __launch_bounds__(256, 4) void k_edge(
    const float* __restrict__ Ha, const float* __restrict__ Hb,
    const float* __restrict__ geom, const float* __restrict__ edges,
    const ushort_t* __restrict__ w2b, const float* __restrict__ b2,
    const ushort_t* __restrict__ pw2b, const float* __restrict__ pb2,
    const ushort_t* __restrict__ pw1b, const float* __restrict__ pb1,
    float* __restrict__ agg0, float* __restrict__ agg1,
    float* __restrict__ pagg0, float* __restrict__ pagg1) {
  int half = blockIdx.x & 1;
  int j = (blockIdx.x >> 1) & 127;
  int b = blockIdx.x >> 8;
  int tid = threadIdx.x;
  int lane = tid & 63;
  int wv = tid >> 6;
  int lrow = lane & 15, lk = lane >> 4;

  __shared__ __align__(16) unsigned char m1s[64*512];   // 32 KB bf16 [64][256]
  __shared__ __align__(16) unsigned char attrB[64*64];  // 4 KB bf16 [64][32]
  __shared__ __align__(16) float HajS[HH];
  __shared__ float wgtS[64];
  __shared__ float gjS[13];

  HajS[tid] = Ha[(b*NN + j)*HH + tid];
  if (tid < 13) gjS[tid] = geom[(b*NN + j)*16 + tid];
  __syncthreads();

  // ---- phase A: edge attrs (bf16, swizzled) + weights (threads 0..63) ----
  if (tid < 64) {
    int il = tid;
    int i = half*64 + il;
    const float* gi = geom + (b*NN + i)*16;
    float dpx = gi[0]-gjS[0], dpy = gi[1]-gjS[1];
    float dvx = gi[2]-gjS[2], dvy = gi[3]-gjS[3];
    float dth = gi[4]-gjS[4];
    float cj = gjS[5], sj = gjS[6];
    float ci = gi[5],  si = gi[6];
    float ndp = sqrtf(dpx*dpx + dpy*dpy + 1e-8f);
    float ndv = sqrtf(dvx*dvx + dvy*dvy + 1e-8f);
    float r1x =  cj*dpx + sj*dpy, r1y = -sj*dpx + cj*dpy;
    float v1x =  cj*dvx + sj*dvy, v1y = -sj*dvx + cj*dvy;
    float r2x = -(ci*dpx + si*dpy), r2y = si*dpx - ci*dpy;
    float v2x = -(ci*dvx + si*dvy), v2y = si*dvx - ci*dvy;
    float f[24];
    f[0]=r1x; f[1]=r1y; f[2]=v1x; f[3]=v1y;
    f[4]=ndp; f[5]=atan2f(r1y, r1x);
    f[6]=ndv; f[7]=atan2f(v1y, v1x); f[8]=dth;
    f[9]=r2x; f[10]=r2y; f[11]=v2x; f[12]=v2y;
    f[13]=ndp; f[14]=atan2f(r2y, r2x);
    f[15]=ndv; f[16]=atan2f(v2y, v2x); f[17]=-dth;
    f[18]=gjS[7]; f[19]=gjS[8]; f[20]=gjS[9];
    f[21]=gjS[10]; f[22]=gjS[11]; f[23]=gjS[12];
    #pragma unroll
    for (int kb = 0; kb < 4; ++kb) {
      bf16x8 v;
      #pragma unroll
      for (int e = 0; e < 8; ++e) {
        int k = kb*8 + e;
        v[e] = (k < 24) ? (short)f2b(f[k]) : (short)0;
      }
      *reinterpret_cast<bf16x8*>(attrB + il*64 + ((kb*16) ^ ((il&3)<<4))) = v;
    }
    float w = 0.f;
    if (i != j) {
      int e = i*127 + (j < i ? j : j-1);
      w = edges[(b*EE + e)*2 + 1];
    }
    wgtS[il] = w;
  }
  __syncthreads();   // HajS fully written before cross-thread reads in B1

  // ---- phase B1 (×2 vectorized): thread handles h-pair hp for 32 rows ----
  {
    int hp = tid & 127;      // h = 2hp, 2hp+1
    int rh = tid >> 7;       // row half: 0 -> rows 0..31, 1 -> rows 32..63
    float2 ha2 = *(const float2*)(HajS + 2*hp);
    const float* hbbase = Hb + (b*NN + half*64 + rh*32)*HH + 2*hp;
    #pragma unroll
    for (int r0 = 0; r0 < 32; r0 += 8) {
      float2 v[8];
      #pragma unroll
      for (int u = 0; u < 8; ++u)
        v[u] = *(const float2*)(hbbase + (r0+u)*HH);
      #pragma unroll
      for (int u = 0; u < 8; ++u) {
        int row = rh*32 + r0 + u;
        uint_t lo = f2b(fast_tanh(ha2.x + v[u].x));
        uint_t hi = f2b(fast_tanh(ha2.y + v[u].y));
        *(uint_t*)(m1s + row*512 + ((hp*4) ^ ((row&15)<<4))) = lo | (hi << 16);
      }
    }
  }
  __syncthreads();

  // preload the 16 weight values this thread's acc rows use (static idx)
  float wreg[16];
  #pragma unroll
  for (int rt = 0; rt < 4; ++rt)
    #pragma unroll
    for (int r = 0; r < 4; ++r)
      wreg[rt*4+r] = wgtS[rt*16 + lk*4 + r];

  // ---- GEMM1: m2 = tanh(m1 @ W2.T + b2); weighted col-sum -> agg partial ---
  {
    f32x4 acc[4][4];
    {
      float bias0 = b2[wv*64 + 0*16 + lrow];
      float bias1 = b2[wv*64 + 1*16 + lrow];
      float bias2 = b2[wv*64 + 2*16 + lrow];
      float bias3 = b2[wv*64 + 3*16 + lrow];
      #pragma unroll
      for (int rt = 0; rt < 4; ++rt) {
        acc[rt][0] = (f32x4){bias0,bias0,bias0,bias0};
        acc[rt][1] = (f32x4){bias1,bias1,bias1,bias1};
        acc[rt][2] = (f32x4){bias2,bias2,bias2,bias2};
        acc[rt][3] = (f32x4){bias3,bias3,bias3,bias3};
      }
    }
    for (int kk = 0; kk < 8; ++kk) {
      bf16x8 afr[4];
      #pragma unroll
      for (int rt = 0; rt < 4; ++rt) {
        int row = rt*16 + lrow;
        afr[rt] = *reinterpret_cast<const bf16x8*>(
            m1s + row*512 + ((kk*64 + lk*16) ^ ((row&15)<<4)));
      }
      #pragma unroll
      for (int nt = 0; nt < 4; ++nt) {
        int col = wv*64 + nt*16 + lrow;
        bf16x8 bfr = *reinterpret_cast<const bf16x8*>(w2b + col*HH + kk*32 + lk*8);
        #pragma unroll
        for (int rt = 0; rt < 4; ++rt)
          acc[rt][nt] = __builtin_amdgcn_mfma_f32_16x16x32_bf16(afr[rt], bfr, acc[rt][nt], 0, 0, 0);
      }
    }
    float* aggOut = half ? agg1 : agg0;
    #pragma unroll
    for (int nt = 0; nt < 4; ++nt) {
      float p = 0.f;
      #pragma unroll
      for (int rt = 0; rt < 4; ++rt)
        #pragma unroll
        for (int r = 0; r < 4; ++r)
          p += fast_tanh(acc[rt][nt][r]) * wreg[rt*4+r];
      p += __shfl_xor(p, 16);
      p += __shfl_xor(p, 32);
      if (lane < 16)
        aggOut[(b*NN + j)*HH + wv*64 + nt*16 + lane] = p * (1.0f/127.0f);
    }
  }
  __syncthreads();

  // ---- phase B2 (MFMA): p1 = relu(attr @ pw1.T + pb1) -> bf16 m1s ---------
  {
    f32x4 acc[4][4];
    {
      float bias0 = pb1[wv*64 + 0*16 + lrow];
      float bias1 = pb1[wv*64 + 1*16 + lrow];
      float bias2 = pb1[wv*64 + 2*16 + lrow];
      float bias3 = pb1[wv*64 + 3*16 + lrow];
      #pragma unroll
      for (int rt = 0; rt < 4; ++rt) {
        acc[rt][0] = (f32x4){bias0,bias0,bias0,bias0};
        acc[rt][1] = (f32x4){bias1,bias1,bias1,bias1};
        acc[rt][2] = (f32x4){bias2,bias2,bias2,bias2};
        acc[rt][3] = (f32x4){bias3,bias3,bias3,bias3};
      }
    }
    bf16x8 afr[4];
    #pragma unroll
    for (int rt = 0; rt < 4; ++rt) {
      int row = rt*16 + lrow;
      afr[rt] = *reinterpret_cast<const bf16x8*>(
          attrB + row*64 + ((lk*16) ^ ((lrow&3)<<4)));
    }
    #pragma unroll
    for (int nt = 0; nt < 4; ++nt) {
      int col = wv*64 + nt*16 + lrow;
      bf16x8 bfr = *reinterpret_cast<const bf16x8*>(pw1b + col*32 + lk*8);
      #pragma unroll
      for (int rt = 0; rt < 4; ++rt)
        acc[rt][nt] = __builtin_amdgcn_mfma_f32_16x16x32_bf16(afr[rt], bfr, acc[rt][nt], 0, 0, 0);
    }
    #pragma unroll
    for (int nt = 0; nt < 4; ++nt) {
      int col = wv*64 + nt*16 + lrow;
      #pragma unroll
      for (int rt = 0; rt < 4; ++rt)
        #pragma unroll
        for (int r = 0; r < 4; ++r) {
          int row = rt*16 + lk*4 + r;
          *(ushort_t*)(m1s + row*512 + ((col*2) ^ ((row&15)<<4))) =
              f2b(fmaxf(acc[rt][nt][r], 0.f));
        }
    }
  }
  __syncthreads();

  // ---- GEMM2: p2 = relu(p1 @ pW2.T + pb2); weighted col-sum -> pagg -------
  {
    f32x4 acc[4][4];
    {
      float bias0 = pb2[wv*64 + 0*16 + lrow];
      float bias1 = pb2[wv*64 + 1*16 + lrow];
      float bias2 = pb2[wv*64 + 2*16 + lrow];
      float bias3 = pb2[wv*64 + 3*16 + lrow];
      #pragma unroll
      for (int rt = 0; rt < 4; ++rt) {
        acc[rt][0] = (f32x4){bias0,bias0,bias0,bias0};
        acc[rt][1] = (f32x4){bias1,bias1,bias1,bias1};
        acc[rt][2] = (f32x4){bias2,bias2,bias2,bias2};
        acc[rt][3] = (f32x4){bias3,bias3,bias3,bias3};
      }
    }
    for (int kk = 0; kk < 8; ++kk) {
      bf16x8 afr[4];
      #pragma unroll
      for (int rt = 0; rt < 4; ++rt) {
        int row = rt*16 + lrow;
        afr[rt] = *reinterpret_cast<const bf16x8*>(
            m1s + row*512 + ((kk*64 + lk*16) ^ ((row&15)<<4)));
      }
      #pragma unroll
      for (int nt = 0; nt < 4; ++nt) {
        int col = wv*64 + nt*16 + lrow;
        bf16x8 bfr = *reinterpret_cast<const bf16x8*>(pw2b + col*HH + kk*32 + lk*8);
        #pragma unroll
        for (int rt = 0; rt < 4; ++rt)
          acc[rt][nt] = __builtin_amdgcn_mfma_f32_16x16x32_bf16(afr[rt], bfr, acc[rt][nt], 0, 0, 0);
      }
    }
    float* paggOut = half ? pagg1 : pagg0;
    #pragma unroll
    for (int nt = 0; nt < 4; ++nt) {
      float p = 0.f;
      #pragma unroll
      for (int rt = 0; rt < 4; ++rt)
        #pragma unroll
        for (int r = 0; r < 4; ++r)
          p += fmaxf(acc[rt][nt][r], 0.f) * wreg[rt*4+r];
      p += __shfl_xor(p, 16);
      p += __shfl_xor(p, 32);
      if (lane < 16)
        paggOut[(b*NN + j)*HH + wv*64 + nt*16 + lane] = p * (1.0f/127.0f);
    }
  }
}

// ---------------------------------------------------------------------------
// K4: GRU gates + output MLP — coalesced packed transposed weights.
// grid 512: block = (node n, batch-quarter), 4 rows.
// ---------------------------------------------------------------------------
__global__ __launch_bounds__(256) void k_gru(
    const float* __restrict__ inputs, const float* __restrict__ hidden,
    const float* __restrict__ geom, const float* __restrict__ relf,
    const float* __restrict__ agg0, const float* __restrict__ agg1,
    const float* __restrict__ pagg0, const float* __restrict__ pagg1,
    const uint_t* __restrict__ wpk,
    const float* __restrict__ pr_b, const float* __restrict__ pi_b,
    const float* __restrict__ pn_b,
    const float* __restrict__ ir_w, const float* __restrict__ ir_b,
    const float* __restrict__ ii_w, const float* __restrict__ ii_b,
    const float* __restrict__ in_w, const float* __restrict__ in_b,
    const float* __restrict__ ob1, const float* __restrict__ ob2,
    const float* __restrict__ ow3, const float* __restrict__ ob3,
    float* __restrict__ out_o, float* __restrict__ out_h) {
  int n = blockIdx.x >> 2, qtr = blockIdx.x & 3;
  int tid = threadIdx.x;
  __shared__ float paS[4][HH], agS[4][HH], hS[4][HH], t0S[4][HH], t1S[4][HH];
  __shared__ float relS[4][16];
  __shared__ float predS[4][4];

  for (int q = 0; q < 4; ++q) {
    int b = qtr*4 + q;
    int base = (b*NN + n)*HH;
    paS[q][tid] = pagg0[base + tid] + pagg1[base + tid];
    agS[q][tid] = agg0[base + tid] + agg1[base + tid];
    hS[q][tid]  = hidden[base + tid];
  }
  if (tid < 64) {
    int q = tid >> 4, k = tid & 15;
    int b = qtr*4 + q;
    relS[q][k] = (k < 15) ? relf[(b*NN + n)*16 + k] : 0.f;
  }
  __syncthreads();

  int h = tid;
  const uint_t* pPr = wpk;
  const uint_t* pPi = wpk + 32768;
  const uint_t* pPn = wpk + 2*32768;
  const uint_t* pHr = wpk + 3*32768;
  const uint_t* pHi = wpk + 4*32768;
  const uint_t* pHh = wpk + 5*32768;
  const uint_t* pO1 = wpk + 6*32768;
  const uint_t* pO2 = wpk + 7*32768;

  float aR[4], aI[4], aN[4], aH[4];
  float br = ir_b[h] + pr_b[h];
  float bi = ii_b[h] + pi_b[h];
  float bn = in_b[h] + pn_b[h];
  #pragma unroll
  for (int q = 0; q < 4; ++q) { aR[q]=br; aI[q]=bi; aN[q]=bn; aH[q]=0.f; }

  for (int k = 0; k < 15; ++k) {
    float wr = ir_w[h*15+k], wi = ii_w[h*15+k], wn = in_w[h*15+k];
    #pragma unroll
    for (int q = 0; q < 4; ++q) {
      float x = relS[q][k];
      aR[q] += x*wr; aI[q] += x*wi; aN[q] += x*wn;
    }
  }

  for (int k2 = 0; k2 < 128; ++k2) {
    uint_t upr = pPr[(k2<<8) + h];
    uint_t upi = pPi[(k2<<8) + h];
    uint_t upn = pPn[(k2<<8) + h];
    uint_t uhr = pHr[(k2<<8) + h];
    uint_t uhi = pHi[(k2<<8) + h];
    uint_t uhh = pHh[(k2<<8) + h];
    float pr0 = blo(upr), pr1 = bhi(upr);
    float pi0 = blo(upi), pi1 = bhi(upi);
    float pn0 = blo(upn), pn1 = bhi(upn);
    float hr0 = blo(uhr), hr1 = bhi(uhr);
    float hi0 = blo(uhi), hi1 = bhi(uhi);
    float hh0 = blo(uhh), hh1 = bhi(uhh);
    int k = k2 << 1;
    #pragma unroll
    for (int q = 0; q < 4; ++q) {
      float2 xp = *(const float2*)(&paS[q][k]);
      float2 xa = *(const float2*)(&agS[q][k]);
      aR[q] += xp.x*pr0 + xp.y*pr1 + xa.x*hr0 + xa.y*hr1;
      aI[q] += xp.x*pi0 + xp.y*pi1 + xa.x*hi0 + xa.y*hi1;
      aN[q] += xp.x*pn0 + xp.y*pn1;
      aH[q] += xa.x*hh0 + xa.y*hh1;
    }
  }

  #pragma unroll
  for (int q = 0; q < 4; ++q) {
    int b = qtr*4 + q;
    float r  = fast_sigmoid(aR[q]);
    float ig = fast_sigmoid(aI[q]);
    float ng = fast_tanh(aN[q] + r*aH[q]);
    float hn = (1.f - ig)*ng + ig*hS[q][h];
    out_h[(b*NN + n)*HH + h] = hn;
    t0S[q][h] = hn;
  }
  __syncthreads();

  { // h1 = relu(hn @ ow1.T + ob1)
    float a1[4];
    float bias = ob1[h];
    #pragma unroll
    for (int q = 0; q < 4; ++q) a1[q] = bias;
    for (int k2 = 0; k2 < 128; ++k2) {
      uint_t u = pO1[(k2<<8) + h];
      float w0 = blo(u), w1 = bhi(u);
      int k = k2 << 1;
      #pragma unroll
      for (int q = 0; q < 4; ++q) {
        float2 x2 = *(const float2*)(&t0S[q][k]);
        a1[q] += x2.x*w0 + x2.y*w1;
      }
    }
    __syncthreads();
    #pragma unroll
    for (int q = 0; q < 4; ++q) t1S[q][h] = fmaxf(a1[q], 0.f);
  }
  __syncthreads();

  { // h2 = relu(h1 @ ow2.T + ob2) -> t0S
    float a2[4];
    float bias = ob2[h];
    #pragma unroll
    for (int q = 0; q < 4; ++q) a2[q] = bias;
    for (int k2 = 0; k2 < 128; ++k2) {
      uint_t u = pO2[(k2<<8) + h];
      float w0 = blo(u), w1 = bhi(u);
      int k = k2 << 1;
      #pragma unroll
      for (int q = 0; q < 4; ++q) {
        float2 x2 = *(const float2*)(&t1S[q][k]);
        a2[q] += x2.x*w0 + x2.y*w1;
      }
    }
    __syncthreads();
    #pragma unroll
    for (int q = 0; q < 4; ++q) t0S[q][h] = fmaxf(a2[q], 0.f);
  }
  __syncthreads();

  if (tid < 16) {
    int o = tid >> 2, q = tid & 3;
    float acc = ob3[o];
    for (int k = 0; k < HH; ++k) acc += t0S[q][k]*ow3[o*HH + k];
    predS[q][o] = acc;
  }
  __syncthreads();
  if (tid < 4) {
    int q = tid;
    int b = qtr*4 + q;
    const float* g = geom + (b*NN + n)*16;
    float c = g[5], s = g[6];
    float p0 = predS[q][0], p1 = predS[q][1], p2 = predS[q][2], p3 = predS[q][3];
    int base = (b*NN + n)*4;
    out_o[base+0] = inputs[base+0] + (c*p0 - s*p1);
    out_o[base+1] = inputs[base+1] + (s*p0 + c*p1);
    out_o[base+2] = inputs[base+2] + (c*p2 - s*p3);
    out_o[base+3] = inputs[base+3] + (s*p2 + c*p3);
  }
}

// ---------------------------------------------------------------------------
extern "C" void kernel_launch(void* const* d_in, const int* in_sizes, int n_in,
                              void* d_out, int out_size, void* d_ws, size_t ws_size,
                              hipStream_t stream) {
  const float* inputs    = (const float*)d_in[0];
  const float* hidden    = (const float*)d_in[1];
  const float* edges     = (const float*)d_in[2];
  const float* pfield    = (const float*)d_in[3];
  const float* msg_fc1_w = (const float*)d_in[4];
  const float* msg_fc1_b = (const float*)d_in[5];
  const float* msg_fc2_w = (const float*)d_in[6];
  const float* msg_fc2_b = (const float*)d_in[7];
  const float* pm_fc1_w  = (const float*)d_in[8];
  const float* pm_fc1_b  = (const float*)d_in[9];
  const float* pm_fc2_w  = (const float*)d_in[10];
  const float* pm_fc2_b  = (const float*)d_in[11];
  const float* hr_w = (const float*)d_in[12];
  const float* hi_w = (const float*)d_in[13];
  const float* hh_w = (const float*)d_in[14];
  const float* pr_w = (const float*)d_in[15];
  const float* pr_b = (const float*)d_in[16];
  const float* pi_w = (const float*)d_in[17];
  const float* pi_b = (const float*)d_in[18];
  const float* pn_w = (const float*)d_in[19];
  const float* pn_b = (const float*)d_in[20];
  const float* ir_w = (const float*)d_in[21];
  const float* ir_b = (const float*)d_in[22];
  const float* ii_w = (const float*)d_in[23];
  const float* ii_b = (const float*)d_in[24];
  const float* in_w = (const float*)d_in[25];
  const float* in_b = (const float*)d_in[26];
  const float* ow1  = (const float*)d_in[27];
  const float* ob1  = (const float*)d_in[28];
  const float* ow2  = (const float*)d_in[29];
  const float* ob2  = (const float*)d_in[30];
  const float* ow3  = (const float*)d_in[31];
  const float* ob3  = (const float*)d_in[32];

  float* ws   = (float*)d_ws;
  float* geom = ws;                 // 32768 f32
  float* relf = geom + 32768;       // 32768
  float* Ha   = relf + 32768;       // 524288
  float* Hb   = Ha   + 524288;      // 524288
  float* agg0 = Hb   + 524288;      // 524288
  float* agg1 = agg0 + 524288;      // 524288
  float* pagg0= agg1 + 524288;      // 524288
  float* pagg1= pagg0+ 524288;      // 524288
  ushort_t* w2b  = (ushort_t*)(pagg1 + 524288);  // 65536 bf16
  ushort_t* pw2b = w2b + HH*HH;                  // 65536 bf16
  ushort_t* pw1b = pw2b + HH*HH;                 // 8192 bf16
  uint_t*   wpk  = (uint_t*)(pw1b + HH*32);      // 10*32768 uint (1.25 MB)

  float* out_o = (float*)d_out;           // (B,N,4)
  float* out_h = out_o + BB*NN*4;         // (B,N,H)

  k_prep<<<dim3(712), dim3(256), 0, stream>>>(inputs, pfield, geom, relf,
      msg_fc2_w, pm_fc2_w, pm_fc1_w + HH*24,
      pr_w, pi_w, pn_w, hr_w, hi_w, hh_w, ow1, ow2,
      msg_fc1_w, w2b, pw2b, pw1b, wpk);
  k_hab<<<dim3(512), dim3(256), 0, stream>>>(hidden, wpk, msg_fc1_b, Ha, Hb);
  k_edge<<<dim3(BB*NN*2), dim3(256), 0, stream>>>(Ha, Hb, geom, edges,
      w2b, msg_fc2_b + HH, pw2b, pm_fc2_b + HH,
      pw1b, pm_fc1_b + HH, agg0, agg1, pagg0, pagg1);
  k_gru<<<dim3(512), dim3(256), 0, stream>>>(inputs, hidden, geom, relf,
      agg0, agg1, pagg0, pagg1, wpk,
      pr_b, pi_b, pn_b, ir_w, ir_b, ii_w, ii_b, in_w, in_b,
      ob1, ob2, ow3, ob3, out_o, out_h);
}